// Round 2
// baseline (562.768 us; speedup 1.0000x reference)
//
#include <hip/hip_runtime.h>
#include <stdint.h>

// Periodic radius-graph neighbor list (AlphaNet). B=16, N=256, C=27, M=6912.
// Outputs (flat f32 concat): dist [B,N,M], dvec [B,N,M,3], num_neighbors_image [B].
// keep = (1e-4 < dsqr <= 25) AND stable-sort rank < 32
//      == key (f32bits(dsqr)<<32 | m) among the 32 smallest within-radius keys.
//
// R11: two-kernel split.
//  - R10 post-mortem: dependency-free zero stream in the fused kernel was
//    NEUTRAL vs R9's gather-merged stream (entire delta = session clock:
//    fill 287.9->306.0 us, x1.0635, 466.5*1.0635=496.2~=496.6 measured).
//    So the store-gather dependency was never the throttle. Remaining
//    difference vs the 6.3 TB/s rocclr fill: barriers (vmcnt(0) drains) and
//    per-block compute interleaved with the stream.
//  - Kernel 1: pure grid-stride zero fill, rocclr-shaped: 4096x256, 27
//    float4 nt stores/thread, no LDS, no barriers. 4096*256*27 ==
//    28,311,552 float4 groups == dist+dvec exactly (453 MB).
//  - Kernel 2: compute + rank + scatter only (~2 MB writes). Barriers run
//    with no stores in flight.
// Predicted: ours ~105 -> ~88 us (fill 73 + compute ~12 + launch ~2).

constexpr int B_ = 16, N_ = 256, C_ = 27;
constexpr int M_ = N_ * C_;      // 6912
constexpr int MAXC = 256;        // candidate slots; mean ~78, 20-sigma safe
constexpr int KMAX = 32;

typedef float vfloat4 __attribute__((ext_vector_type(4)));

// ---- kernel 1: pure zero fill, rocclr-fill-shaped -------------------------
__global__ __launch_bounds__(256)
void zero_fill(float* __restrict__ out)   // covers dist[B,N,M] ++ dvec[B,N,M,3]
{
    vfloat4 z; z.x = 0.f; z.y = 0.f; z.z = 0.f; z.w = 0.f;
    vfloat4* p = (vfloat4*)out + ((size_t)blockIdx.x * 256 + threadIdx.x);
    // 4096 blocks * 256 threads * 27 iters == 28,311,552 groups exactly.
    #pragma unroll
    for (int k = 0; k < 27; ++k) {
        __builtin_nontemporal_store(z, p);
        p += (size_t)4096 * 256;
    }
}

// ---- kernel 2: compute + rank + scatter -----------------------------------
__global__ __launch_bounds__(256)
void nbr_compute(const float* __restrict__ pos,    // [B,N,3]
                 const float* __restrict__ cell,   // [B,3,3]
                 float* __restrict__ dist,         // [B,N,M] (pre-zeroed)
                 float* __restrict__ dvec,         // [B,N,M,3] (pre-zeroed)
                 float* __restrict__ nn)           // [B] (pre-zeroed)
{
#pragma clang fp contract(off)
    __shared__ float offx[C_], offy[C_], offz[C_];
    __shared__ unsigned long long keys[MAXC];
    __shared__ float4 vals[MAXC];               // dx,dy,dz,dsq
    __shared__ float4 kept[KMAX];               // dx,dy,dz,dist (by rank)
    __shared__ int    keptm[KMAX];              // candidate index m (by rank)
    __shared__ int cnt;

    const int bi  = blockIdx.x;   // b*N + i
    const int b   = bi >> 8;
    const int i   = bi & 255;
    const int tid = threadIdx.x;

    const float* pb = pos + b * N_ * 3;
    const float pjx = pb[tid * 3 + 0], pjy = pb[tid * 3 + 1], pjz = pb[tid * 3 + 2];
    const float pix = pb[i * 3 + 0],   piy = pb[i * 3 + 1],   piz = pb[i * 3 + 2];

    if (tid < C_) {
        const float n1 = (float)(tid / 9 - 1);
        const float n2 = (float)((tid / 3) % 3 - 1);
        const float n3 = (float)(tid % 3 - 1);
        const float* cb = cell + b * 9;
        offx[tid] = n1 * cb[0] + n2 * cb[3] + n3 * cb[6];
        offy[tid] = n1 * cb[1] + n2 * cb[4] + n3 * cb[7];
        offz[tid] = n1 * cb[2] + n2 * cb[5] + n3 * cb[8];
    }
    if (tid == 0) cnt = 0;
    __syncthreads();

    // pass 1: bit-exact numpy order: s = pj + off; d = pi - s;
    // ((dx*dx+dy*dy)+dz*dz), contract off.
    #pragma unroll 1
    for (int c = 0; c < C_; ++c) {
        const float sx = pjx + offx[c], sy = pjy + offy[c], sz = pjz + offz[c];
        const float dx = pix - sx, dy = piy - sy, dz = piz - sz;
        const float dsq = dx * dx + dy * dy + dz * dz;
        if (dsq <= 25.0f && dsq > 1e-4f) {
            const int idx = atomicAdd(&cnt, 1);              // LDS atomic
            if (idx < MAXC) {
                keys[idx] = ((unsigned long long)__float_as_uint(dsq) << 32)
                          | (unsigned)(tid * C_ + c);
                vals[idx] = make_float4(dx, dy, dz, dsq);
            }
        }
    }
    __syncthreads();

    int K = cnt; if (K > MAXC) K = MAXC;
    const int nk = K < KMAX ? K : KMAX;
    if (tid == 0)
        atomicAdd(&nn[b], (float)nk);

    // ranking -> compact kept list (keys unique since m unique; each rank
    // r in [0,nk) written exactly once).
    for (int idx = tid; idx < K; idx += 256) {
        const unsigned long long key = keys[idx];
        int r = 0;
        for (int q = 0; q < K; ++q) r += (keys[q] < key) ? 1 : 0;
        if (r < KMAX) {
            const float4 v = vals[idx];
            kept[r]  = make_float4(v.x, v.y, v.z, sqrtf(v.w));
            keptm[r] = (int)(key & 0xffffffffu);
        }
    }
    __syncthreads();

    if (tid < nk) {
        const float4 v = kept[tid];
        const int m = keptm[tid];
        float* drow = dist + (size_t)bi * M_;
        float* vrow = dvec + (size_t)bi * (size_t)(M_ * 3) + 3 * m;
        drow[m] = v.w;
        vrow[0] = v.x;
        vrow[1] = v.y;
        vrow[2] = v.z;
    }
}

extern "C" void kernel_launch(void* const* d_in, const int* in_sizes, int n_in,
                              void* d_out, int out_size, void* d_ws, size_t ws_size,
                              hipStream_t stream)
{
    const float* pos  = (const float*)d_in[0];
    const float* cell = (const float*)d_in[1];
    float* dist = (float*)d_out;
    float* dvec = dist + (size_t)B_ * N_ * M_;
    float* nn   = dvec + (size_t)B_ * N_ * M_ * 3;
    (void)hipMemsetAsync(nn, 0, B_ * sizeof(float), stream);   // zero count tail only
    zero_fill<<<dim3(4096), dim3(256), 0, stream>>>(dist);     // dist++dvec, 453 MB
    nbr_compute<<<dim3(B_ * N_), dim3(256), 0, stream>>>(pos, cell, dist, dvec, nn);
}

// Round 3
// 471.877 us; speedup vs baseline: 1.1926x; 1.1926x over previous
//
#include <hip/hip_runtime.h>
#include <stdint.h>

// Periodic radius-graph neighbor list (AlphaNet). B=16, N=256, C=27, M=6912.
// Outputs (flat f32 concat): dist [B,N,M], dvec [B,N,M,3], num_neighbors_image [B].
// keep = (1e-4 < dsqr <= 25) AND stable-sort rank < 32
//      == key (f32bits(dsqr)<<32 | m) among the 32 smallest within-radius keys.
//
// R12 = R10 fused structure with ONE change: nontemporal stores -> plain
// cached stores.
//  - R10 post-mortem: dependency-free zero stream == R9 gather-merged stream
//    (store deps not the throttle). R11 post-mortem: standalone rocclr-shaped
//    fill kernel + separate compute kernel was +66 us (split serialization,
//    and the "pure" fill STILL didn't hit rocclr rate).
//  - Common untested variable across R9/R10/R11: __builtin_nontemporal_store.
//    rocclr fill (6.3 TB/s) and the 6.29 TB/s copy ubench use PLAIN stores
//    through L2 with bulk writeback; nt bypasses L2 write-combining.
//  - Bonus: phase-C scatter now merges into still-dirty L2 zero lines
//    instead of HBM read-modify-write.
// Predicted: ours ~110 -> ~82 us; total ~470 at fill~306 clocks.

constexpr int B_ = 16, N_ = 256, C_ = 27;
constexpr int M_ = N_ * C_;      // 6912
constexpr int MAXC = 256;        // candidate slots; mean ~78, 20-sigma safe
constexpr int KMAX = 32;

typedef float vfloat4 __attribute__((ext_vector_type(4)));

__global__ __launch_bounds__(256)
void nbr_kernel(const float* __restrict__ pos,    // [B,N,3]
                const float* __restrict__ cell,   // [B,3,3]
                float* __restrict__ dist,         // [B,N,M]
                float* __restrict__ dvec,         // [B,N,M,3]
                float* __restrict__ nn)           // [B] (float counts, pre-zeroed)
{
#pragma clang fp contract(off)
    __shared__ float offx[C_], offy[C_], offz[C_];
    __shared__ unsigned long long keys[MAXC];
    __shared__ float4 vals[MAXC];               // dx,dy,dz,dsq
    __shared__ float4 kept[KMAX];               // dx,dy,dz,dist (by rank)
    __shared__ int    keptm[KMAX];              // candidate index m (by rank)
    __shared__ int cnt;

    const int bi  = blockIdx.x;   // b*N + i
    const int b   = bi >> 8;
    const int i   = bi & 255;
    const int tid = threadIdx.x;

    const float* pb = pos + b * N_ * 3;
    const float pjx = pb[tid * 3 + 0], pjy = pb[tid * 3 + 1], pjz = pb[tid * 3 + 2];
    const float pix = pb[i * 3 + 0],   piy = pb[i * 3 + 1],   piz = pb[i * 3 + 2];

    float* drow = dist + (size_t)bi * M_;
    float* vrow = dvec + (size_t)bi * (size_t)(M_ * 3);

    // ---- phase A: zero stream, PLAIN stores (L2 write-combining path).
    // dist row: 1728 float4 = 6*256 + 192 ; dvec row: 5184 float4 = 20*256 + 64.
    {
        vfloat4 z; z.x = 0.f; z.y = 0.f; z.z = 0.f; z.w = 0.f;
        #pragma unroll
        for (int k = 0; k < 6; ++k)
            *(vfloat4*)(drow + 4 * (tid + k * 256)) = z;
        if (tid < 192)
            *(vfloat4*)(drow + 4 * (1536 + tid)) = z;
        #pragma unroll
        for (int k = 0; k < 20; ++k)
            *(vfloat4*)(vrow + 4 * (tid + k * 256)) = z;
        if (tid < 64)
            *(vfloat4*)(vrow + 4 * (5120 + tid)) = z;
    }

    if (tid < C_) {
        const float n1 = (float)(tid / 9 - 1);
        const float n2 = (float)((tid / 3) % 3 - 1);
        const float n3 = (float)(tid % 3 - 1);
        const float* cb = cell + b * 9;
        offx[tid] = n1 * cb[0] + n2 * cb[3] + n3 * cb[6];
        offy[tid] = n1 * cb[1] + n2 * cb[4] + n3 * cb[7];
        offz[tid] = n1 * cb[2] + n2 * cb[5] + n3 * cb[8];
    }
    if (tid == 0) cnt = 0;
    __syncthreads();

    // ---- phase B1: bit-exact numpy order: s = pj + off; d = pi - s;
    // ((dx*dx+dy*dy)+dz*dz), contract off.
    #pragma unroll 1
    for (int c = 0; c < C_; ++c) {
        const float sx = pjx + offx[c], sy = pjy + offy[c], sz = pjz + offz[c];
        const float dx = pix - sx, dy = piy - sy, dz = piz - sz;
        const float dsq = dx * dx + dy * dy + dz * dz;
        if (dsq <= 25.0f && dsq > 1e-4f) {
            const int idx = atomicAdd(&cnt, 1);              // LDS atomic
            if (idx < MAXC) {
                keys[idx] = ((unsigned long long)__float_as_uint(dsq) << 32)
                          | (unsigned)(tid * C_ + c);
                vals[idx] = make_float4(dx, dy, dz, dsq);
            }
        }
    }
    __syncthreads();

    int K = cnt; if (K > MAXC) K = MAXC;
    const int nk = K < KMAX ? K : KMAX;
    if (tid == 0)
        atomicAdd(&nn[b], (float)nk);

    // ---- phase B2: ranking -> compact kept list (keys unique since m unique;
    // each rank r in [0,nk) written exactly once).
    for (int idx = tid; idx < K; idx += 256) {
        const unsigned long long key = keys[idx];
        int r = 0;
        for (int q = 0; q < K; ++q) r += (keys[q] < key) ? 1 : 0;
        if (r < KMAX) {
            const float4 v = vals[idx];
            kept[r]  = make_float4(v.x, v.y, v.z, sqrtf(v.w));
            keptm[r] = (int)(key & 0xffffffffu);
        }
    }

    // ---- phase C: barrier orders phase-A zero stores before fix-up stores;
    // with plain stores the zero lines are still dirty in L2 so the scatter
    // merges there (no HBM RMW).
    __syncthreads();

    if (tid < nk) {
        const float4 v = kept[tid];
        const int m = keptm[tid];
        drow[m]         = v.w;      // dist
        float* vp = vrow + 3 * m;   // dvec
        vp[0] = v.x;
        vp[1] = v.y;
        vp[2] = v.z;
    }
}

extern "C" void kernel_launch(void* const* d_in, const int* in_sizes, int n_in,
                              void* d_out, int out_size, void* d_ws, size_t ws_size,
                              hipStream_t stream)
{
    const float* pos  = (const float*)d_in[0];
    const float* cell = (const float*)d_in[1];
    float* dist = (float*)d_out;
    float* dvec = dist + (size_t)B_ * N_ * M_;
    float* nn   = dvec + (size_t)B_ * N_ * M_ * 3;
    (void)hipMemsetAsync(nn, 0, B_ * sizeof(float), stream);   // zero count tail only
    nbr_kernel<<<dim3(B_ * N_), dim3(256), 0, stream>>>(pos, cell, dist, dvec, nn);
}